// Round 1
// baseline (434.622 us; speedup 1.0000x reference)
//
#include <hip/hip_runtime.h>

#define IN_DIM 128
#define HID 64

// ---------------- degree count ----------------
__global__ void k_count(const int* __restrict__ dst, int E, int* __restrict__ deg) {
    int e = blockIdx.x * blockDim.x + threadIdx.x;
    if (e < E) atomicAdd(&deg[dst[e]], 1);
}

// ---------------- exclusive scan (single block) + dis = rsqrt(deg+1) ----------------
__global__ __launch_bounds__(1024) void k_scan(const int* __restrict__ deg, int N,
                                               int* __restrict__ row_start,
                                               float* __restrict__ dis) {
    __shared__ int buf[2][1024];
    __shared__ int carry_s;
    int tid = threadIdx.x;
    if (tid == 0) carry_s = 0;
    __syncthreads();
    int nchunk = (N + 1023) / 1024;
    for (int c = 0; c < nchunk; ++c) {
        int idx = c * 1024 + tid;
        int v = (idx < N) ? deg[idx] : 0;
        buf[0][tid] = v;
        __syncthreads();
        int pb = 0;
        for (int off = 1; off < 1024; off <<= 1) {
            int t = buf[pb][tid];
            if (tid >= off) t += buf[pb][tid - off];
            buf[pb ^ 1][tid] = t;
            pb ^= 1;
            __syncthreads();
        }
        int inc = buf[pb][tid];      // inclusive scan of this chunk
        int carry = carry_s;
        if (idx < N) {
            row_start[idx] = carry + inc - v;   // exclusive
            dis[idx] = rsqrtf((float)(v + 1));  // +1 self loop
        }
        int tot = buf[pb][1023];
        __syncthreads();
        if (tid == 0) carry_s = carry + tot;
        __syncthreads();
    }
    if (tid == 0) row_start[N] = carry_s;
}

// ---------------- CSR fill (counting sort by dst) ----------------
__global__ void k_fill(const int* __restrict__ src, const int* __restrict__ dst, int E,
                       const int* __restrict__ row_start, int* __restrict__ cursor,
                       int* __restrict__ csr_src) {
    int e = blockIdx.x * blockDim.x + threadIdx.x;
    if (e < E) {
        int d = dst[e];
        int pos = atomicAdd(&cursor[d], 1);
        csr_src[row_start[d] + pos] = src[e];
    }
}

// ---------------- GEMM [N,K] x [K,64], scaled by dis[row] ----------------
template <int K>
__global__ __launch_bounds__(256) void k_gemm_scale(const float* __restrict__ X,
                                                    const float* __restrict__ W,
                                                    const float* __restrict__ dis, int N,
                                                    float* __restrict__ out) {
    __shared__ float Wl[K * HID];
    int tid = threadIdx.x;
    for (int i = tid; i < K * HID; i += 256) Wl[i] = W[i];
    __syncthreads();
    int wave = tid >> 6, lane = tid & 63;
    int row = blockIdx.x * 4 + wave;
    if (row >= N) return;
    const float* xr = X + (size_t)row * K;
    float acc = 0.f;
#pragma unroll 8
    for (int k = 0; k < K; ++k) acc += xr[k] * Wl[k * HID + lane];
    out[(size_t)row * HID + lane] = acc * dis[row];
}

// ---------------- gather-aggregate: out[i] = relu(dis[i]*(Hs[i] + sum Hs[src]) + b) ----------------
__global__ __launch_bounds__(256) void k_aggregate(const float* __restrict__ Hs,
                                                   const int* __restrict__ row_start,
                                                   const int* __restrict__ csr_src,
                                                   const float* __restrict__ dis,
                                                   const float* __restrict__ bias, int N,
                                                   int do_relu, float* __restrict__ out) {
    int wave = threadIdx.x >> 6, lane = threadIdx.x & 63;
    int node = blockIdx.x * 4 + wave;
    if (node >= N) return;
    float acc = Hs[(size_t)node * HID + lane];  // self loop
    int e0 = row_start[node], e1 = row_start[node + 1];
    for (int e = e0; e < e1; ++e) {
        int s = csr_src[e];
        acc += Hs[(size_t)s * HID + lane];
    }
    float v = acc * dis[node] + bias[lane];
    if (do_relu) v = fmaxf(v, 0.f);
    out[(size_t)node * HID + lane] = v;
}

// ---------------- head: logits = h @ Wl + bl  ([N,64]x[64,2]) ----------------
__global__ __launch_bounds__(256) void k_final(const float* __restrict__ H,
                                               const float* __restrict__ Wl,
                                               const float* __restrict__ bl, int N,
                                               float* __restrict__ out) {
    int wave = threadIdx.x >> 6, lane = threadIdx.x & 63;
    int node = blockIdx.x * 4 + wave;
    if (node >= N) return;
    float h = H[(size_t)node * HID + lane];
    float a0 = h * Wl[lane * 2 + 0];
    float a1 = h * Wl[lane * 2 + 1];
    for (int off = 32; off; off >>= 1) {
        a0 += __shfl_down(a0, off);
        a1 += __shfl_down(a1, off);
    }
    if (lane == 0) {
        out[node * 2 + 0] = a0 + bl[0];
        out[node * 2 + 1] = a1 + bl[1];
    }
}

extern "C" void kernel_launch(void* const* d_in, const int* in_sizes, int n_in,
                              void* d_out, int out_size, void* d_ws, size_t ws_size,
                              hipStream_t stream) {
    const float* x  = (const float*)d_in[0];
    const int*   ei = (const int*)d_in[1];
    const float* W1 = (const float*)d_in[2];
    const float* b1 = (const float*)d_in[3];
    const float* W2 = (const float*)d_in[4];
    const float* b2 = (const float*)d_in[5];
    const float* Wl = (const float*)d_in[6];
    const float* bl = (const float*)d_in[7];

    const int N = in_sizes[0] / IN_DIM;   // 50000
    const int E = in_sizes[1] / 2;        // 800000
    const int* src = ei;
    const int* dst = ei + E;

    // workspace layout
    char* ws = (char*)d_ws;
    size_t off = 0;
    auto alloc = [&](size_t bytes) -> void* {
        void* p = ws + off;
        off = (off + bytes + 255) & ~(size_t)255;
        return p;
    };
    int*   deg       = (int*)alloc((size_t)N * 4);
    int*   row_start = (int*)alloc(((size_t)N + 1) * 4);
    int*   cursor    = (int*)alloc((size_t)N * 4);
    int*   csr_src   = (int*)alloc((size_t)E * 4);
    float* dis       = (float*)alloc((size_t)N * 4);
    float* bufA      = (float*)alloc((size_t)N * HID * 4);  // Hs
    float* bufB      = (float*)alloc((size_t)N * HID * 4);  // h

    hipMemsetAsync(deg, 0, (size_t)N * 4, stream);
    hipMemsetAsync(cursor, 0, (size_t)N * 4, stream);

    k_count<<<(E + 255) / 256, 256, 0, stream>>>(dst, E, deg);
    k_scan<<<1, 1024, 0, stream>>>(deg, N, row_start, dis);
    k_fill<<<(E + 255) / 256, 256, 0, stream>>>(src, dst, E, row_start, cursor, csr_src);

    int nblk = (N + 3) / 4;
    // layer 1
    k_gemm_scale<IN_DIM><<<nblk, 256, 0, stream>>>(x, W1, dis, N, bufA);
    k_aggregate<<<nblk, 256, 0, stream>>>(bufA, row_start, csr_src, dis, b1, N, 1, bufB);
    // layer 2
    k_gemm_scale<HID><<<nblk, 256, 0, stream>>>(bufB, W2, dis, N, bufA);
    k_aggregate<<<nblk, 256, 0, stream>>>(bufA, row_start, csr_src, dis, b2, N, 1, bufB);
    // head
    k_final<<<nblk, 256, 0, stream>>>(bufB, Wl, bl, N, (float*)d_out);
}